// Round 23
// baseline (125.680 us; speedup 1.0000x reference)
//
#include <hip/hip_runtime.h>
#include <hip/hip_bf16.h>
#include <math.h>
#include <stdint.h>

#define B 2
#define N 2048
#define C 1024
#define H 16
#define D 64
#define LN_EPS 1e-5f

typedef unsigned short u16;
typedef unsigned int u32;
typedef __attribute__((ext_vector_type(8))) short b16x8;
typedef __attribute__((ext_vector_type(4))) float f32x4;

#define MFMA(a, b, c) __builtin_amdgcn_mfma_f32_16x16x32_bf16(a, b, c, 0, 0, 0)
#define VMCNT(n) asm volatile("s_waitcnt vmcnt(" #n ")" ::: "memory")
#define LGKM0()  asm volatile("s_waitcnt lgkmcnt(0)" ::: "memory")

__device__ __forceinline__ u16 f2bf(float x) {
    u32 u = __float_as_uint(x);
    u32 r = u + 0x7fff + ((u >> 16) & 1);   // RNE
    return (u16)(r >> 16);
}
__device__ __forceinline__ float bf2f(u16 v) {
    return __uint_as_float(((u32)v) << 16);
}
__device__ __forceinline__ void gload_lds16(const void* g, void* l) {
    __builtin_amdgcn_global_load_lds(
        (__attribute__((address_space(1))) void*)(uintptr_t)g,
        (__attribute__((address_space(3))) void*)l, 16, 0, 0);
}
__device__ __forceinline__ float exp2_asm(float x) {
    float r;
    asm("v_exp_f32 %0, %1" : "=v"(r) : "v"(x));
    return r;
}
__device__ __forceinline__ u32 cvtpk_bf16(float lo, float hi) {
    u32 r;
    asm("v_cvt_pk_bf16_f32 %0, %1, %2" : "=v"(r) : "v"(lo), "v"(hi));
    return r;
}

union PW { u32 w[4]; b16x8 v; };

// ------- fused cast fp32 -> bf16 (x, qkv_w, proj_w) + RoPE cos/sin table ----
__global__ __launch_bounds__(256) void castk3(
    const float* __restrict__ a, u16* __restrict__ oa, int na4,
    const float* __restrict__ b, u16* __restrict__ ob, int nb4,
    const float* __restrict__ c, u16* __restrict__ oc, int nc4,
    float* __restrict__ ropetab, const int* __restrict__ pos)
{
    int i = blockIdx.x * 256 + threadIdx.x;
    const float* src; u16* dst; int off;
    if (i < na4) { src = a; dst = oa; off = i; }
    else if (i < na4 + nb4) { src = b; dst = ob; off = i - na4; }
    else if (i < na4 + nb4 + nc4) { src = c; dst = oc; off = i - na4 - nb4; }
    else {
        const int idx = i - (na4 + nb4 + nc4);
        if (idx < N * 32) {
            const int nn = idx >> 5, d2 = idx & 31;
            const float invf = exp2_asm((float)d2 * -0.41524101186092029f);
            const float ang = (float)pos[nn] * invf;
            float2 cs;
            cs.x = cosf(ang);
            cs.y = sinf(ang);
            *(float2*)&ropetab[2 * idx] = cs;
        }
        return;
    }
    float4 v = ((const float4*)src)[off];
    ushort4 o;
    o.x = f2bf(v.x); o.y = f2bf(v.y); o.z = f2bf(v.z); o.w = f2bf(v.w);
    ((ushort4*)dst)[off] = o;
}

// ---------------- bf16 MFMA GEMM, BK=64, 3-buffer counted-vmcnt -------------
// R23: BK=64 (R22's proven nt-halving) + R17-style counted-vmcnt pipeline:
// stage(t) gets TWO compute windows (>= HBM 900cyc); barrier waits only
// VMCNT(6) = tile-t's own 6 loads (long retired). stage(t+2) issued post-
// barrier into the buffer last read at compute(t-1) (race-free by barrier).
// Chunk swizzle = attn-K pattern (0-conflict): stage cg = ch^(r&7), read
// chunk (ks*4+g)^(c&7). T1 row-chunk XCD swizzle. MF=2, NF=4 both GEMMs.
// MODE 0: fused LN+RoPE epilogue. LDS 72KB -> 2 blocks/CU (pipeline vs TLP).
template <int MODE, int MF, int NF>
__global__ __launch_bounds__(256) void mfma_gemm(
    const u16* __restrict__ A, const u16* __restrict__ W,
    float* __restrict__ outp, const float* __restrict__ bias,
    u16* __restrict__ qkb, u16* __restrict__ vbuf,
    const float* __restrict__ qnw, const float* __restrict__ qnb,
    const float* __restrict__ knw, const float* __restrict__ knb,
    const float* __restrict__ ropetab, int K)
{
    __shared__ u16 As[3][(32 * MF) * 64];
    __shared__ u16 Ws[3][(32 * NF) * 64];
    const int tid = threadIdx.x;
    const int lane = tid & 63, wave = tid >> 6;
    const int g = lane >> 4, c = lane & 15;
    const int wr = wave >> 1, wc = wave & 1;

    // --- T1 bijective XCD swizzle (grid size % 8 == 0), row-chunk ---
    const int nwg = gridDim.x * gridDim.y;
    const int p = blockIdx.x + gridDim.x * blockIdx.y;
    const int bidr = (p & 7) * (nwg >> 3) + (p >> 3);
    const int row0 = (bidr / gridDim.x) * (32 * MF);
    const int col0 = (bidr % gridDim.x) * (32 * NF);

    f32x4 acc[MF][NF];
    #pragma unroll
    for (int m = 0; m < MF; ++m)
        #pragma unroll
        for (int n = 0; n < NF; ++n) acc[m][n] = (f32x4){0.f, 0.f, 0.f, 0.f};

    // stage one BK=64 tile (MF+NF=6 gloads/thread), source pre-swizzled
    auto stage = [&](int k0, int bi) {
        #pragma unroll
        for (int rep = 0; rep < MF; ++rep) {
            const int idx = rep * 256 + tid;
            const int r_ = idx >> 3, ch = idx & 7;
            const int cg = ch ^ (r_ & 7);
            gload_lds16(A + (size_t)(row0 + r_) * K + k0 + cg * 8,
                        As[bi] + (size_t)idx * 8);
        }
        #pragma unroll
        for (int rep = 0; rep < NF; ++rep) {
            const int idx = rep * 256 + tid;
            const int r_ = idx >> 3, ch = idx & 7;
            const int cg = ch ^ (r_ & 7);
            gload_lds16(W + (size_t)(col0 + r_) * K + k0 + cg * 8,
                        Ws[bi] + (size_t)idx * 8);
        }
    };

    const int nt = K / 64;                   // 16
    stage(0, 0);                             // outstanding 6
    stage(64, 1);                            // outstanding 12
    for (int t = 0; t < nt; ++t) {
        const int bi = t % 3;
        if (t + 1 < nt) { VMCNT(6); } else { VMCNT(0); }
        __builtin_amdgcn_s_barrier();        // tile t fully in LDS (all waves)
        if (t + 2 < nt) stage((t + 2) * 64, (t + 2) % 3);

        b16x8 af[MF][2], wf[NF][2];
        #pragma unroll
        for (int ks = 0; ks < 2; ++ks) {
            const int chsl = ((ks * 4 + g) ^ (c & 7)) * 8;
            #pragma unroll
            for (int m = 0; m < MF; ++m)
                af[m][ks] = *(const b16x8*)&As[bi][(wr * 16 * MF + m * 16 + c) * 64 + chsl];
            #pragma unroll
            for (int n = 0; n < NF; ++n)
                wf[n][ks] = *(const b16x8*)&Ws[bi][(wc * 16 * NF + n * 16 + c) * 64 + chsl];
        }
        #pragma unroll
        for (int m = 0; m < MF; ++m)
            #pragma unroll
            for (int n = 0; n < NF; ++n) {
                acc[m][n] = MFMA(af[m][0], wf[n][0], acc[m][n]);
                acc[m][n] = MFMA(af[m][1], wf[n][1], acc[m][n]);
            }
    }

    if (MODE == 0) {
        const int colbase = col0 + wc * 16 * NF;       // multiple of 64 (NF=4)
        const int which = colbase >> 10;               // 0=q 1=k 2=v
        const int hh = (colbase >> 6) & (H - 1);
        if (which == 2) {
            #pragma unroll
            for (int m = 0; m < MF; ++m)
                #pragma unroll
                for (int n = 0; n < NF; ++n)
                    #pragma unroll
                    for (int r = 0; r < 4; ++r) {
                        const int row = row0 + wr * 16 * MF + m * 16 + g * 4 + r;
                        const int bb = row >> 11, nn = row & (N - 1);
                        vbuf[(((size_t)(bb * H + hh)) * N + nn) * 64 + n * 16 + c] =
                            f2bf(acc[m][n][r]);
                    }
        } else {
            const float* wv = which ? knw : qnw;
            const float* bv = which ? knb : qnb;
            float wl[4], bl[4];
            #pragma unroll
            for (int n = 0; n < 4; ++n) { wl[n] = wv[n * 16 + c]; bl[n] = bv[n * 16 + c]; }
            const float qs = which ? 1.0f : 0.18033688011112042f;  // 0.125*log2(e)
            u16* dst = qkb + (size_t)which * (B * H * N * D);
            #pragma unroll
            for (int m = 0; m < MF; ++m)
                #pragma unroll
                for (int r = 0; r < 4; ++r) {
                    const float v0 = acc[m][0][r], v1 = acc[m][1][r];
                    const float v2 = acc[m][2][r], v3 = acc[m][3][r];
                    float s = (v0 + v1) + (v2 + v3);
                    s += __shfl_xor(s, 1, 64); s += __shfl_xor(s, 2, 64);
                    s += __shfl_xor(s, 4, 64); s += __shfl_xor(s, 8, 64);
                    const float mu = s * (1.0f / 64.0f);
                    const float d0 = v0 - mu, d1 = v1 - mu;
                    const float d2_ = v2 - mu, d3 = v3 - mu;
                    float s2 = (d0 * d0 + d1 * d1) + (d2_ * d2_ + d3 * d3);
                    s2 += __shfl_xor(s2, 1, 64); s2 += __shfl_xor(s2, 2, 64);
                    s2 += __shfl_xor(s2, 4, 64); s2 += __shfl_xor(s2, 8, 64);
                    const float rstd = rsqrtf(s2 * (1.0f / 64.0f) + LN_EPS);
                    const float y0 = d0 * rstd * wl[0] + bl[0];
                    const float y1 = d1 * rstd * wl[1] + bl[1];
                    const float y2 = d2_ * rstd * wl[2] + bl[2];
                    const float y3 = d3 * rstd * wl[3] + bl[3];
                    const int row = row0 + wr * 16 * MF + m * 16 + g * 4 + r;
                    const int bb = row >> 11, nn = row & (N - 1);
                    const float2 csa = *(const float2*)&ropetab[(size_t)nn * 64 + 2 * c];
                    const float2 csb = *(const float2*)&ropetab[(size_t)nn * 64 + 2 * (16 + c)];
                    const float o0 = (y0 * csa.x - y2 * csa.y) * qs;
                    const float o2 = (y0 * csa.y + y2 * csa.x) * qs;
                    const float o1 = (y1 * csb.x - y3 * csb.y) * qs;
                    const float o3 = (y1 * csb.y + y3 * csb.x) * qs;
                    u16* rp = dst + (((size_t)(bb * H + hh)) * N + nn) * 64;
                    rp[0 * 16 + c] = f2bf(o0);
                    rp[1 * 16 + c] = f2bf(o1);
                    rp[2 * 16 + c] = f2bf(o2);
                    rp[3 * 16 + c] = f2bf(o3);
                }
        }
    } else {
        #pragma unroll
        for (int m = 0; m < MF; ++m)
            #pragma unroll
            for (int n = 0; n < NF; ++n)
                #pragma unroll
                for (int r = 0; r < 4; ++r) {
                    const int row = row0 + wr * 16 * MF + m * 16 + g * 4 + r;
                    const int col = col0 + wc * 16 * NF + n * 16 + c;
                    outp[(size_t)row * C + col] = acc[m][n][r] + bias[col];
                }
    }
}

// ---------------- attention: 8 waves x 16 q-rows, q-tile 128, KVBLK 64 ------
// [round-17 verified structure, byte-identical — T4 counted-vmcnt schedule]
__global__ __launch_bounds__(512, 2) void attn_kernel(
    const u16* __restrict__ qkb, const u16* __restrict__ vb, u16* __restrict__ aout)
{
    __shared__ u16 Kl[2][2][64 * 64]; // [pair-buf][half]: [j][d], chunks XOR (j&7)
    __shared__ u16 Vt[2][2][64 * 64]; // [pair-buf][half]: round-5 verified bijection
    const int tid = threadIdx.x, lane = tid & 63, wave = tid >> 6;
    const int g = lane >> 4, c = lane & 15;
    const int p_ = blockIdx.x;                       // 512 blocks
    const int bid = (p_ & 7) * 64 + (p_ >> 3);       // XCD-contiguous heads
    const int qt = bid & 15, h = (bid >> 4) & 15, b = bid >> 8;
    const size_t headbase = ((size_t)(b * H + h)) * N * D;
    const u16* Qg = qkb + headbase;
    const u16* Kg = qkb + (size_t)(B * H * N * D) + headbase;
    const u16* Vg = vb + headbase;
    const int q0 = qt * 128 + wave * 16;

    b16x8 qf[2];
    #pragma unroll
    for (int ks = 0; ks < 2; ++ks)
        qf[ks] = *(const b16x8*)&Qg[(size_t)(q0 + c) * 64 + ks * 32 + g * 8];

    f32x4 oacc[4];                    // oacc[Dg][r] = O^T[d=Dg*16+4g+r][q=q0+c]
    #pragma unroll
    for (int nd = 0; nd < 4; ++nd) oacc[nd] = (f32x4){0.f, 0.f, 0.f, 0.f};
    float l_part = 0.f;               // per-lane partial; reduced in epilogue

    auto stageK = [&](int kt, u16* dstbuf) {
        const int j = tid >> 3, cc2 = tid & 7;
        const int cg = cc2 ^ (j & 7);
        gload_lds16(Kg + (size_t)(kt * 64 + j) * 64 + cg * 8,
                    dstbuf + (size_t)tid * 8);
    };

    const int vjp = (tid & 31) * 2;
    const int vdg = (tid >> 5) & 7;
    const int vddh = tid >> 8;
    const int vchunk16 = 4 * (vjp >> 5) + ((vjp >> 2) & 3);
    const int vpos = 4 * ((vjp >> 4) & 1) + (vjp & 3);
    ushort4 vA4[2], vB4[2];
    auto loadV2 = [&](int pair) {     // tiles 2*pair, 2*pair+1 (4 vmem loads)
        #pragma unroll
        for (int t = 0; t < 2; ++t) {
            const int kt = 2 * pair + t;
            vA4[t] = *(const ushort4*)&Vg[(size_t)(kt * 64 + vjp) * 64 + vdg * 8 + vddh * 4];
            vB4[t] = *(const ushort4*)&Vg[(size_t)(kt * 64 + vjp + 1) * 64 + vdg * 8 + vddh * 4];
        }
    };
    auto writeV2 = [&](int bi) {
        #pragma unroll
        for (int t = 0; t < 2; ++t) {
            const u16 a_[4] = {vA4[t].x, vA4[t].y, vA4[t].z, vA4[t].w};
            const u16 b_[4] = {vB4[t].x, vB4[t].y, vB4[t].z, vB4[t].w};
            #pragma unroll
            for (int i = 0; i < 4; ++i) {
                const int dd = vddh * 4 + i;               // = d & 7
                const int d = vdg * 8 + dd;
                const u32 pk = (u32)a_[i] | ((u32)b_[i] << 16);
                *(u32*)((char*)Vt[bi][t] + d * 128 + ((vchunk16 ^ dd) << 4) + vpos * 2) = pk;
            }
        }
    };

    auto compute = [&](const char* Kb, const char* Vb) {
        f32x4 s[4];
        #pragma unroll
        for (int jt = 0; jt < 4; ++jt) s[jt] = (f32x4){0.f, 0.f, 0.f, 0.f};
        __builtin_amdgcn_s_setprio(1);
        #pragma unroll
        for (int jt = 0; jt < 4; ++jt)
            #pragma unroll
            for (int ks = 0; ks < 2; ++ks) {
                const int byteoff = (jt * 16 + c) * 128 + ((ks * 64 + g * 16) ^ ((c & 7) << 4));
                const b16x8 kf = *(const b16x8*)(Kb + byteoff);
                s[jt] = MFMA(kf, qf[ks], s[jt]);
            }
        __builtin_amdgcn_s_setprio(0);

        float psj[4];
        #pragma unroll
        for (int jt = 0; jt < 4; ++jt) {
            #pragma unroll
            for (int r = 0; r < 4; ++r) s[jt][r] = exp2_asm(s[jt][r]);
            psj[jt] = (s[jt][0] + s[jt][1]) + (s[jt][2] + s[jt][3]);
        }
        l_part += (psj[0] + psj[1]) + (psj[2] + psj[3]);

        PW pw[2];
        #pragma unroll
        for (int ks = 0; ks < 2; ++ks)
            #pragma unroll
            for (int wd = 0; wd < 4; ++wd)
                pw[ks].w[wd] = cvtpk_bf16(s[2 * ks + (wd >> 1)][2 * (wd & 1)],
                                          s[2 * ks + (wd >> 1)][2 * (wd & 1) + 1]);

        __builtin_amdgcn_s_setprio(1);
        #pragma unroll
        for (int Dg = 0; Dg < 4; ++Dg) {
            #pragma unroll
            for (int kh = 0; kh < 2; ++kh) {
                const b16x8 vf = *(const b16x8*)(Vb + Dg * 2048 + c * 128 +
                                                 (((4 * kh + g) ^ (c & 7)) << 4));
                oacc[Dg] = MFMA(vf, pw[kh].v, oacc[Dg]);
            }
        }
        __builtin_amdgcn_s_setprio(0);
    };

    // prologue: pair 0 -> buffer 0. After this: outstanding = 2 (K_0 stages)
    loadV2(0);                            // +4 (V_0)
    stageK(0, (u16*)Kl[0][0]);            // +1
    stageK(1, (u16*)Kl[0][1]);            // +2 -> 6
    VMCNT(2);                             // drain V_0 regs (oldest 4)
    writeV2(0);                           // Vt[0] ds_writes

    const int npair = N / 128;            // 16
    for (int p = 0; p < npair - 1; ++p) {
        const int bi = p & 1;
        loadV2(p + 1);                    // +4 (V_{p+1}) -> outstanding 6
        VMCNT(4);                         // drain pair-p K stages (2 oldest)
        LGKM0();                          // own V_p ds_writes retired
        __builtin_amdgcn_s_barrier();     // all waves: pair p fully in LDS
        stageK(2 * p + 2, (u16*)Kl[bi ^ 1][0]);   // safe post-barrier overwrite
        stageK(2 * p + 3, (u16*)Kl[bi ^ 1][1]);   // -> outstanding 6
        compute((const char*)Kl[bi][0], (const char*)Vt[bi][0]);
        compute((const char*)Kl[bi][1], (const char*)Vt[bi][1]);
        VMCNT(2);                         // V_{p+1} regs ready; K stays in flight
        writeV2(bi ^ 1);                  // Vt[bi^1] (not read until next barrier)
    }
    // tail: pair 15 in buffer 1; outstanding = 2 (its K stages)
    VMCNT(0);
    LGKM0();
    __builtin_amdgcn_s_barrier();
    compute((const char*)Kl[1][0], (const char*)Vt[1][0]);
    compute((const char*)Kl[1][1], (const char*)Vt[1][1]);

    // --- epilogue: reduce l across g-groups (q = c is shared), then store ---
    float l = l_part;
    l += __shfl_xor(l, 16, 64);
    l += __shfl_xor(l, 32, 64);
    const float li = 1.0f / l;
    #pragma unroll
    for (int Dg = 0; Dg < 4; ++Dg) {
        uint2 pr;
        pr.x = cvtpk_bf16(oacc[Dg][0] * li, oacc[Dg][1] * li);
        pr.y = cvtpk_bf16(oacc[Dg][2] * li, oacc[Dg][3] * li);
        *(uint2*)&aout[((size_t)(b * N + q0 + c)) * C + h * 64 + Dg * 16 + g * 4] = pr;
    }
}

extern "C" void kernel_launch(void* const* d_in, const int* in_sizes, int n_in,
                              void* d_out, int out_size, void* d_ws, size_t ws_size,
                              hipStream_t stream) {
    const float* x      = (const float*)d_in[0];
    const float* qkv_w  = (const float*)d_in[1];
    const float* qn_w   = (const float*)d_in[2];
    const float* qn_b   = (const float*)d_in[3];
    const float* kn_w   = (const float*)d_in[4];
    const float* kn_b   = (const float*)d_in[5];
    const float* proj_w = (const float*)d_in[6];
    const float* proj_b = (const float*)d_in[7];
    const int*   pos    = (const int*)d_in[8];
    float* out = (float*)d_out;

    u16* xb      = (u16*)d_ws;                 // 4096x1024
    u16* wqkvb   = xb + 4194304;               // 3072x1024
    u16* wprojb  = wqkvb + 3145728;            // 1024x1024
    u16* qkb     = wprojb + 1048576;           // [2][B][H][N][D]
    u16* vbuf    = qkb + 8388608;              // [B][H][N][D]
    u16* aob     = vbuf + 4194304;             // [B][N][C]
    float* rtab  = (float*)(aob + 4194304);    // [N][32][2] cos/sin

    castk3<<<8448, 256, 0, stream>>>(x, xb, 1048576,
                                     qkv_w, wqkvb, 786432,
                                     proj_w, wprojb, 262144,
                                     rtab, pos);

    // QKV: BM=64, BN=128, BK=64, 3-buf -> grid 24x64, 72KB LDS (2/CU)
    mfma_gemm<0, 2, 4><<<dim3(24, 64), 256, 0, stream>>>(
        xb, wqkvb, nullptr, nullptr, qkb, vbuf,
        qn_w, qn_b, kn_w, kn_b, rtab, C);
    attn_kernel<<<512, 512, 0, stream>>>(qkb, vbuf, aob);
    // proj: BM=64, BN=128, BK=64, 3-buf -> grid 8x64 = 512 blocks, 72KB LDS
    mfma_gemm<1, 2, 4><<<dim3(8, 64), 256, 0, stream>>>(
        aob, wprojb, out, proj_b, nullptr, nullptr,
        nullptr, nullptr, nullptr, nullptr, nullptr, C);
}

// Round 24
// 112.117 us; speedup vs baseline: 1.1210x; 1.1210x over previous
//
#include <hip/hip_runtime.h>
#include <hip/hip_bf16.h>
#include <math.h>
#include <stdint.h>

#define B 2
#define N 2048
#define C 1024
#define H 16
#define D 64
#define LN_EPS 1e-5f

typedef unsigned short u16;
typedef unsigned int u32;
typedef __attribute__((ext_vector_type(8))) short b16x8;
typedef __attribute__((ext_vector_type(4))) float f32x4;

#define MFMA(a, b, c) __builtin_amdgcn_mfma_f32_16x16x32_bf16(a, b, c, 0, 0, 0)
#define VMCNT(n) asm volatile("s_waitcnt vmcnt(" #n ")" ::: "memory")
#define LGKM0()  asm volatile("s_waitcnt lgkmcnt(0)" ::: "memory")

__device__ __forceinline__ u16 f2bf(float x) {
    u32 u = __float_as_uint(x);
    u32 r = u + 0x7fff + ((u >> 16) & 1);   // RNE
    return (u16)(r >> 16);
}
__device__ __forceinline__ float bf2f(u16 v) {
    return __uint_as_float(((u32)v) << 16);
}
__device__ __forceinline__ void gload_lds16(const void* g, void* l) {
    __builtin_amdgcn_global_load_lds(
        (__attribute__((address_space(1))) void*)(uintptr_t)g,
        (__attribute__((address_space(3))) void*)l, 16, 0, 0);
}
__device__ __forceinline__ float exp2_asm(float x) {
    float r;
    asm("v_exp_f32 %0, %1" : "=v"(r) : "v"(x));
    return r;
}
__device__ __forceinline__ u32 cvtpk_bf16(float lo, float hi) {
    u32 r;
    asm("v_cvt_pk_bf16_f32 %0, %1, %2" : "=v"(r) : "v"(lo), "v"(hi));
    return r;
}

union PW { u32 w[4]; b16x8 v; };

// ------- fused cast fp32 -> bf16 (x, qkv_w, proj_w) + RoPE cos/sin table ----
__global__ __launch_bounds__(256) void castk3(
    const float* __restrict__ a, u16* __restrict__ oa, int na4,
    const float* __restrict__ b, u16* __restrict__ ob, int nb4,
    const float* __restrict__ c, u16* __restrict__ oc, int nc4,
    float* __restrict__ ropetab, const int* __restrict__ pos)
{
    int i = blockIdx.x * 256 + threadIdx.x;
    const float* src; u16* dst; int off;
    if (i < na4) { src = a; dst = oa; off = i; }
    else if (i < na4 + nb4) { src = b; dst = ob; off = i - na4; }
    else if (i < na4 + nb4 + nc4) { src = c; dst = oc; off = i - na4 - nb4; }
    else {
        const int idx = i - (na4 + nb4 + nc4);
        if (idx < N * 32) {
            const int nn = idx >> 5, d2 = idx & 31;
            const float invf = exp2_asm((float)d2 * -0.41524101186092029f);
            const float ang = (float)pos[nn] * invf;
            float2 cs;
            cs.x = cosf(ang);
            cs.y = sinf(ang);
            *(float2*)&ropetab[2 * idx] = cs;
        }
        return;
    }
    float4 v = ((const float4*)src)[off];
    ushort4 o;
    o.x = f2bf(v.x); o.y = f2bf(v.y); o.z = f2bf(v.z); o.w = f2bf(v.w);
    ((ushort4*)dst)[off] = o;
}

// ---------------- bf16 MFMA GEMM, 2-phase dbuf, BK=64 ----------------------
// [round-22 verified config, byte-identical — best measured: 112.3 us total]
// nt = K/64 = 16 (halved drain-latency exposure vs BK=32 — the R22 win).
// Chunk swizzle = attn-K pattern (measured 0-conflict): stage cg = ch^(r&7),
// read chunk = (ks*4+g)^(c&7) -> 8 chunks x 4 banks, 2 lanes each.
// T1 row-chunk XCD swizzle. MODE 0 (NF=4): fused LN+RoPE epilogue.
template <int MODE, int MF, int NF>
__global__ __launch_bounds__(256) void mfma_gemm(
    const u16* __restrict__ A, const u16* __restrict__ W,
    float* __restrict__ outp, const float* __restrict__ bias,
    u16* __restrict__ qkb, u16* __restrict__ vbuf,
    const float* __restrict__ qnw, const float* __restrict__ qnb,
    const float* __restrict__ knw, const float* __restrict__ knb,
    const float* __restrict__ ropetab, int K)
{
    __shared__ u16 As[2][(32 * MF) * 64];
    __shared__ u16 Ws[2][(32 * NF) * 64];
    const int tid = threadIdx.x;
    const int lane = tid & 63, wave = tid >> 6;
    const int g = lane >> 4, c = lane & 15;
    const int wr = wave >> 1, wc = wave & 1;

    // --- T1 bijective XCD swizzle (grid size % 8 == 0), row-chunk ---
    const int nwg = gridDim.x * gridDim.y;
    const int p = blockIdx.x + gridDim.x * blockIdx.y;
    const int bidr = (p & 7) * (nwg >> 3) + (p >> 3);
    const int row0 = (bidr / gridDim.x) * (32 * MF);
    const int col0 = (bidr % gridDim.x) * (32 * NF);

    f32x4 acc[MF][NF];
    #pragma unroll
    for (int m = 0; m < MF; ++m)
        #pragma unroll
        for (int n = 0; n < NF; ++n) acc[m][n] = (f32x4){0.f, 0.f, 0.f, 0.f};

    // stage one BK=64 tile: rows x 8 chunks of 16B, source pre-swizzled
    auto stage = [&](int k0, int bi) {
        #pragma unroll
        for (int rep = 0; rep < MF; ++rep) {
            const int idx = rep * 256 + tid;
            const int r_ = idx >> 3, ch = idx & 7;
            const int cg = ch ^ (r_ & 7);
            gload_lds16(A + (size_t)(row0 + r_) * K + k0 + cg * 8,
                        As[bi] + (size_t)idx * 8);
        }
        #pragma unroll
        for (int rep = 0; rep < NF; ++rep) {
            const int idx = rep * 256 + tid;
            const int r_ = idx >> 3, ch = idx & 7;
            const int cg = ch ^ (r_ & 7);
            gload_lds16(W + (size_t)(col0 + r_) * K + k0 + cg * 8,
                        Ws[bi] + (size_t)idx * 8);
        }
    };

    stage(0, 0);
    __syncthreads();
    const int nt = K / 64;                   // 16
    for (int t = 0; t < nt; ++t) {
        const int bi = t & 1;
        if (t + 1 < nt) stage((t + 1) * 64, bi ^ 1);

        b16x8 af[MF][2], wf[NF][2];
        #pragma unroll
        for (int ks = 0; ks < 2; ++ks) {
            const int chsl = ((ks * 4 + g) ^ (c & 7)) * 8;
            #pragma unroll
            for (int m = 0; m < MF; ++m)
                af[m][ks] = *(const b16x8*)&As[bi][(wr * 16 * MF + m * 16 + c) * 64 + chsl];
            #pragma unroll
            for (int n = 0; n < NF; ++n)
                wf[n][ks] = *(const b16x8*)&Ws[bi][(wc * 16 * NF + n * 16 + c) * 64 + chsl];
        }
        #pragma unroll
        for (int m = 0; m < MF; ++m)
            #pragma unroll
            for (int n = 0; n < NF; ++n) {
                acc[m][n] = MFMA(af[m][0], wf[n][0], acc[m][n]);
                acc[m][n] = MFMA(af[m][1], wf[n][1], acc[m][n]);
            }
        __syncthreads();
    }

    if (MODE == 0) {
        const int colbase = col0 + wc * 16 * NF;       // multiple of 64 (NF=4)
        const int which = colbase >> 10;               // 0=q 1=k 2=v
        const int hh = (colbase >> 6) & (H - 1);
        if (which == 2) {
            #pragma unroll
            for (int m = 0; m < MF; ++m)
                #pragma unroll
                for (int n = 0; n < NF; ++n)
                    #pragma unroll
                    for (int r = 0; r < 4; ++r) {
                        const int row = row0 + wr * 16 * MF + m * 16 + g * 4 + r;
                        const int bb = row >> 11, nn = row & (N - 1);
                        vbuf[(((size_t)(bb * H + hh)) * N + nn) * 64 + n * 16 + c] =
                            f2bf(acc[m][n][r]);
                    }
        } else {
            const float* wv = which ? knw : qnw;
            const float* bv = which ? knb : qnb;
            float wl[4], bl[4];
            #pragma unroll
            for (int n = 0; n < 4; ++n) { wl[n] = wv[n * 16 + c]; bl[n] = bv[n * 16 + c]; }
            const float qs = which ? 1.0f : 0.18033688011112042f;  // 0.125*log2(e)
            u16* dst = qkb + (size_t)which * (B * H * N * D);
            #pragma unroll
            for (int m = 0; m < MF; ++m)
                #pragma unroll
                for (int r = 0; r < 4; ++r) {
                    const float v0 = acc[m][0][r], v1 = acc[m][1][r];
                    const float v2 = acc[m][2][r], v3 = acc[m][3][r];
                    float s = (v0 + v1) + (v2 + v3);
                    s += __shfl_xor(s, 1, 64); s += __shfl_xor(s, 2, 64);
                    s += __shfl_xor(s, 4, 64); s += __shfl_xor(s, 8, 64);
                    const float mu = s * (1.0f / 64.0f);
                    const float d0 = v0 - mu, d1 = v1 - mu;
                    const float d2_ = v2 - mu, d3 = v3 - mu;
                    float s2 = (d0 * d0 + d1 * d1) + (d2_ * d2_ + d3 * d3);
                    s2 += __shfl_xor(s2, 1, 64); s2 += __shfl_xor(s2, 2, 64);
                    s2 += __shfl_xor(s2, 4, 64); s2 += __shfl_xor(s2, 8, 64);
                    const float rstd = rsqrtf(s2 * (1.0f / 64.0f) + LN_EPS);
                    const float y0 = d0 * rstd * wl[0] + bl[0];
                    const float y1 = d1 * rstd * wl[1] + bl[1];
                    const float y2 = d2_ * rstd * wl[2] + bl[2];
                    const float y3 = d3 * rstd * wl[3] + bl[3];
                    const int row = row0 + wr * 16 * MF + m * 16 + g * 4 + r;
                    const int bb = row >> 11, nn = row & (N - 1);
                    const float2 csa = *(const float2*)&ropetab[(size_t)nn * 64 + 2 * c];
                    const float2 csb = *(const float2*)&ropetab[(size_t)nn * 64 + 2 * (16 + c)];
                    const float o0 = (y0 * csa.x - y2 * csa.y) * qs;
                    const float o2 = (y0 * csa.y + y2 * csa.x) * qs;
                    const float o1 = (y1 * csb.x - y3 * csb.y) * qs;
                    const float o3 = (y1 * csb.y + y3 * csb.x) * qs;
                    u16* rp = dst + (((size_t)(bb * H + hh)) * N + nn) * 64;
                    rp[0 * 16 + c] = f2bf(o0);
                    rp[1 * 16 + c] = f2bf(o1);
                    rp[2 * 16 + c] = f2bf(o2);
                    rp[3 * 16 + c] = f2bf(o3);
                }
        }
    } else {
        #pragma unroll
        for (int m = 0; m < MF; ++m)
            #pragma unroll
            for (int n = 0; n < NF; ++n)
                #pragma unroll
                for (int r = 0; r < 4; ++r) {
                    const int row = row0 + wr * 16 * MF + m * 16 + g * 4 + r;
                    const int col = col0 + wc * 16 * NF + n * 16 + c;
                    outp[(size_t)row * C + col] = acc[m][n][r] + bias[col];
                }
    }
}

// ---------------- attention: 8 waves x 16 q-rows, q-tile 128, KVBLK 64 ------
// [round-17 verified structure, byte-identical — T4 counted-vmcnt schedule]
__global__ __launch_bounds__(512, 2) void attn_kernel(
    const u16* __restrict__ qkb, const u16* __restrict__ vb, u16* __restrict__ aout)
{
    __shared__ u16 Kl[2][2][64 * 64]; // [pair-buf][half]: [j][d], chunks XOR (j&7)
    __shared__ u16 Vt[2][2][64 * 64]; // [pair-buf][half]: round-5 verified bijection
    const int tid = threadIdx.x, lane = tid & 63, wave = tid >> 6;
    const int g = lane >> 4, c = lane & 15;
    const int p_ = blockIdx.x;                       // 512 blocks
    const int bid = (p_ & 7) * 64 + (p_ >> 3);       // XCD-contiguous heads
    const int qt = bid & 15, h = (bid >> 4) & 15, b = bid >> 8;
    const size_t headbase = ((size_t)(b * H + h)) * N * D;
    const u16* Qg = qkb + headbase;
    const u16* Kg = qkb + (size_t)(B * H * N * D) + headbase;
    const u16* Vg = vb + headbase;
    const int q0 = qt * 128 + wave * 16;

    b16x8 qf[2];
    #pragma unroll
    for (int ks = 0; ks < 2; ++ks)
        qf[ks] = *(const b16x8*)&Qg[(size_t)(q0 + c) * 64 + ks * 32 + g * 8];

    f32x4 oacc[4];                    // oacc[Dg][r] = O^T[d=Dg*16+4g+r][q=q0+c]
    #pragma unroll
    for (int nd = 0; nd < 4; ++nd) oacc[nd] = (f32x4){0.f, 0.f, 0.f, 0.f};
    float l_part = 0.f;               // per-lane partial; reduced in epilogue

    auto stageK = [&](int kt, u16* dstbuf) {
        const int j = tid >> 3, cc2 = tid & 7;
        const int cg = cc2 ^ (j & 7);
        gload_lds16(Kg + (size_t)(kt * 64 + j) * 64 + cg * 8,
                    dstbuf + (size_t)tid * 8);
    };

    const int vjp = (tid & 31) * 2;
    const int vdg = (tid >> 5) & 7;
    const int vddh = tid >> 8;
    const int vchunk16 = 4 * (vjp >> 5) + ((vjp >> 2) & 3);
    const int vpos = 4 * ((vjp >> 4) & 1) + (vjp & 3);
    ushort4 vA4[2], vB4[2];
    auto loadV2 = [&](int pair) {     // tiles 2*pair, 2*pair+1 (4 vmem loads)
        #pragma unroll
        for (int t = 0; t < 2; ++t) {
            const int kt = 2 * pair + t;
            vA4[t] = *(const ushort4*)&Vg[(size_t)(kt * 64 + vjp) * 64 + vdg * 8 + vddh * 4];
            vB4[t] = *(const ushort4*)&Vg[(size_t)(kt * 64 + vjp + 1) * 64 + vdg * 8 + vddh * 4];
        }
    };
    auto writeV2 = [&](int bi) {
        #pragma unroll
        for (int t = 0; t < 2; ++t) {
            const u16 a_[4] = {vA4[t].x, vA4[t].y, vA4[t].z, vA4[t].w};
            const u16 b_[4] = {vB4[t].x, vB4[t].y, vB4[t].z, vB4[t].w};
            #pragma unroll
            for (int i = 0; i < 4; ++i) {
                const int dd = vddh * 4 + i;               // = d & 7
                const int d = vdg * 8 + dd;
                const u32 pk = (u32)a_[i] | ((u32)b_[i] << 16);
                *(u32*)((char*)Vt[bi][t] + d * 128 + ((vchunk16 ^ dd) << 4) + vpos * 2) = pk;
            }
        }
    };

    auto compute = [&](const char* Kb, const char* Vb) {
        f32x4 s[4];
        #pragma unroll
        for (int jt = 0; jt < 4; ++jt) s[jt] = (f32x4){0.f, 0.f, 0.f, 0.f};
        __builtin_amdgcn_s_setprio(1);
        #pragma unroll
        for (int jt = 0; jt < 4; ++jt)
            #pragma unroll
            for (int ks = 0; ks < 2; ++ks) {
                const int byteoff = (jt * 16 + c) * 128 + ((ks * 64 + g * 16) ^ ((c & 7) << 4));
                const b16x8 kf = *(const b16x8*)(Kb + byteoff);
                s[jt] = MFMA(kf, qf[ks], s[jt]);
            }
        __builtin_amdgcn_s_setprio(0);

        float psj[4];
        #pragma unroll
        for (int jt = 0; jt < 4; ++jt) {
            #pragma unroll
            for (int r = 0; r < 4; ++r) s[jt][r] = exp2_asm(s[jt][r]);
            psj[jt] = (s[jt][0] + s[jt][1]) + (s[jt][2] + s[jt][3]);
        }
        l_part += (psj[0] + psj[1]) + (psj[2] + psj[3]);

        PW pw[2];
        #pragma unroll
        for (int ks = 0; ks < 2; ++ks)
            #pragma unroll
            for (int wd = 0; wd < 4; ++wd)
                pw[ks].w[wd] = cvtpk_bf16(s[2 * ks + (wd >> 1)][2 * (wd & 1)],
                                          s[2 * ks + (wd >> 1)][2 * (wd & 1) + 1]);

        __builtin_amdgcn_s_setprio(1);
        #pragma unroll
        for (int Dg = 0; Dg < 4; ++Dg) {
            #pragma unroll
            for (int kh = 0; kh < 2; ++kh) {
                const b16x8 vf = *(const b16x8*)(Vb + Dg * 2048 + c * 128 +
                                                 (((4 * kh + g) ^ (c & 7)) << 4));
                oacc[Dg] = MFMA(vf, pw[kh].v, oacc[Dg]);
            }
        }
        __builtin_amdgcn_s_setprio(0);
    };

    // prologue: pair 0 -> buffer 0. After this: outstanding = 2 (K_0 stages)
    loadV2(0);                            // +4 (V_0)
    stageK(0, (u16*)Kl[0][0]);            // +1
    stageK(1, (u16*)Kl[0][1]);            // +2 -> 6
    VMCNT(2);                             // drain V_0 regs (oldest 4)
    writeV2(0);                           // Vt[0] ds_writes

    const int npair = N / 128;            // 16
    for (int p = 0; p < npair - 1; ++p) {
        const int bi = p & 1;
        loadV2(p + 1);                    // +4 (V_{p+1}) -> outstanding 6
        VMCNT(4);                         // drain pair-p K stages (2 oldest)
        LGKM0();                          // own V_p ds_writes retired
        __builtin_amdgcn_s_barrier();     // all waves: pair p fully in LDS
        stageK(2 * p + 2, (u16*)Kl[bi ^ 1][0]);   // safe post-barrier overwrite
        stageK(2 * p + 3, (u16*)Kl[bi ^ 1][1]);   // -> outstanding 6
        compute((const char*)Kl[bi][0], (const char*)Vt[bi][0]);
        compute((const char*)Kl[bi][1], (const char*)Vt[bi][1]);
        VMCNT(2);                         // V_{p+1} regs ready; K stays in flight
        writeV2(bi ^ 1);                  // Vt[bi^1] (not read until next barrier)
    }
    // tail: pair 15 in buffer 1; outstanding = 2 (its K stages)
    VMCNT(0);
    LGKM0();
    __builtin_amdgcn_s_barrier();
    compute((const char*)Kl[1][0], (const char*)Vt[1][0]);
    compute((const char*)Kl[1][1], (const char*)Vt[1][1]);

    // --- epilogue: reduce l across g-groups (q = c is shared), then store ---
    float l = l_part;
    l += __shfl_xor(l, 16, 64);
    l += __shfl_xor(l, 32, 64);
    const float li = 1.0f / l;
    #pragma unroll
    for (int Dg = 0; Dg < 4; ++Dg) {
        uint2 pr;
        pr.x = cvtpk_bf16(oacc[Dg][0] * li, oacc[Dg][1] * li);
        pr.y = cvtpk_bf16(oacc[Dg][2] * li, oacc[Dg][3] * li);
        *(uint2*)&aout[((size_t)(b * N + q0 + c)) * C + h * 64 + Dg * 16 + g * 4] = pr;
    }
}

extern "C" void kernel_launch(void* const* d_in, const int* in_sizes, int n_in,
                              void* d_out, int out_size, void* d_ws, size_t ws_size,
                              hipStream_t stream) {
    const float* x      = (const float*)d_in[0];
    const float* qkv_w  = (const float*)d_in[1];
    const float* qn_w   = (const float*)d_in[2];
    const float* qn_b   = (const float*)d_in[3];
    const float* kn_w   = (const float*)d_in[4];
    const float* kn_b   = (const float*)d_in[5];
    const float* proj_w = (const float*)d_in[6];
    const float* proj_b = (const float*)d_in[7];
    const int*   pos    = (const int*)d_in[8];
    float* out = (float*)d_out;

    u16* xb      = (u16*)d_ws;                 // 4096x1024
    u16* wqkvb   = xb + 4194304;               // 3072x1024
    u16* wprojb  = wqkvb + 3145728;            // 1024x1024
    u16* qkb     = wprojb + 1048576;           // [2][B][H][N][D]
    u16* vbuf    = qkb + 8388608;              // [B][H][N][D]
    u16* aob     = vbuf + 4194304;             // [B][N][C]
    float* rtab  = (float*)(aob + 4194304);    // [N][32][2] cos/sin

    castk3<<<8448, 256, 0, stream>>>(x, xb, 1048576,
                                     qkv_w, wqkvb, 786432,
                                     proj_w, wprojb, 262144,
                                     rtab, pos);

    // QKV: BM=64, BN=128, BK=64 -> grid 24x64 = 1536 blocks, 48KB LDS (3/CU)
    mfma_gemm<0, 2, 4><<<dim3(24, 64), 256, 0, stream>>>(
        xb, wqkvb, nullptr, nullptr, qkb, vbuf,
        qn_w, qn_b, kn_w, kn_b, rtab, C);
    attn_kernel<<<512, 512, 0, stream>>>(qkb, vbuf, aob);
    // proj: BM=64, BN=64, BK=64 -> grid 16x64 = 1024 blocks, 32KB LDS (5/CU)
    mfma_gemm<1, 2, 2><<<dim3(16, 64), 256, 0, stream>>>(
        aob, wprojb, out, proj_b, nullptr, nullptr,
        nullptr, nullptr, nullptr, nullptr, nullptr, C);
}